// Round 6
// baseline (3056.777 us; speedup 1.0000x reference)
//
#include <hip/hip_runtime.h>
#include <cmath>

#define NR   8192   // rows of Y
#define DB   512    // signal dim n
#define NB   2048   // dictionary atoms m
#define ITERS 20
#define NSQ   9     // trace-normalized squarings of B

typedef _Float16 hfrag_t __attribute__((ext_vector_type(8)));  // 8 fp16 (4 VGPRs)
typedef __attribute__((ext_vector_type(4))) float accv_t;      // 4 fp32
typedef unsigned short us4 __attribute__((ext_vector_type(4))); // 8B
typedef float f4 __attribute__((ext_vector_type(4)));           // 16B

union frag_cv { us4 u[2]; hfrag_t h; };

// scalar slots in ws
#define SL_Y2   0
#define SL_NUM  1
#define SL_DEN  2
#define SL_C    3
#define SL_ETA  4
#define SL_THR  5
#define SL_TR   6    // 6..15  traces
#define SL_RES2 16   // 16..35 per-iter ||R||^2

__device__ inline unsigned short f2h(float f) {
  _Float16 h = (_Float16)f;
  return __builtin_bit_cast(unsigned short, h);
}
__device__ inline float h2f(unsigned short u) {
  _Float16 h = __builtin_bit_cast(_Float16, u);
  return (float)h;
}
__device__ inline float softthr(float x, float t) {
  float a = fabsf(x) - t;
  return a > 0.f ? copysignf(a, x) : 0.f;
}

struct TC { int wm, wn, l16, quad; };
__device__ inline TC tcoords() {
  int tid = threadIdx.x; int w = tid >> 6, lane = tid & 63;
  TC c; c.wm = (w >> 1) << 6; c.wn = (w & 1) << 6; c.l16 = lane & 15; c.quad = lane >> 4;
  return c;
}

// Tiled fp16 layout: 16x16 tile = 256 contiguous elems; element (m=l16, n=q*4+r)
// at tilebase + (q*16 + l16)*4 + r. A wave's epilogue us4 = tilebase + lane*4.
__device__ inline size_t tbase(int m16, int n16, int NT) {
  return ((size_t)((m16 >> 4) * NT + (n16 >> 4))) << 8;
}

// async global->LDS, 16 bytes per lane; LDS dest = wave-uniform base + lane*16
__device__ inline void gld_lds16(const unsigned short* g, unsigned short* l) {
  __builtin_amdgcn_global_load_lds(
      (const __attribute__((address_space(1))) unsigned int*)g,
      (__attribute__((address_space(3))) unsigned int*)l,
      16, 0, 0);
}

// ---- MFMA GEMM core, tiled-A, double-buffered B ----
// C tile = A (tiled, NTa k-tiles/row) * B (n-major Bn[N][K]); BN fixed 128.
// wm/wn: wave offsets within block tile. PF: register-prefetch A one kt ahead.
// Operand-swapped MFMA: lane owns m = l16 (fixed), n = quad*4 + r.
template<int MI, int NI, int PF>
__device__ inline void gemm_tA_db(const unsigned short* __restrict__ At, int NTa,
                                  const unsigned short* __restrict__ Bn, int K,
                                  int m0, int n0, int wm, int wn, accv_t acc[MI][NI]) {
  __shared__ unsigned short ldsB[2][128 * 32];
  const int tid = threadIdx.x;
  const int wave = tid >> 6, lane = tid & 63;
  const int l16 = lane & 15, quad = lane >> 4;
  const int qb = (quad & 1) << 1;
  const int khalf = quad >> 1;
  const int inoff = (qb * 16 + l16) << 2;
  const int mt0 = (m0 + wm) >> 4;

#pragma unroll
  for (int mi = 0; mi < MI; ++mi)
#pragma unroll
    for (int ni = 0; ni < NI; ++ni) acc[mi][ni] = (accv_t){0.f, 0.f, 0.f, 0.f};

  const int nkt = K >> 5;

  auto stageB = [&](int kt, int buf) {
    const int k0 = kt << 5;
#pragma unroll
    for (int it = 0; it < 2; ++it) {
      int cbase = (it << 8) + (wave << 6);     // wave-uniform chunk base
      int chunk = cbase + lane;
      int row = chunk >> 2, kc = (chunk & 3) << 3;
      gld_lds16(&Bn[(size_t)(n0 + row) * K + k0 + kc], &ldsB[buf][cbase * 8]);
    }
  };
  auto loadA = [&](int kt, hfrag_t af[MI]) {
    const int ktile = (kt << 1) + khalf;
#pragma unroll
    for (int mi = 0; mi < MI; ++mi) {
      const us4* bp = (const us4*)&At[((((size_t)(mt0 + mi)) * NTa + ktile) << 8) + inoff];
      frag_cv cv; cv.u[0] = bp[0]; cv.u[1] = bp[16];
      af[mi] = cv.h;
    }
  };

  hfrag_t acur[MI], anext[MI];
  if (PF) loadA(0, acur);
  stageB(0, 0);
  for (int kt = 0; kt < nkt; ++kt) {
    __syncthreads();                 // drains B-stage (and A loads) issued last iter
    if (kt + 1 < nkt) {
      stageB(kt + 1, (kt + 1) & 1);  // in flight through this iteration's compute
      if (PF) loadA(kt + 1, anext);
    }
    if (!PF) loadA(kt, acur);
    hfrag_t bf[NI];
#pragma unroll
    for (int ni = 0; ni < NI; ++ni)
      bf[ni] = *(const hfrag_t*)&ldsB[kt & 1][(wn + ni * 16 + l16) * 32 + quad * 8];
#pragma unroll
    for (int mi = 0; mi < MI; ++mi)
#pragma unroll
      for (int ni = 0; ni < NI; ++ni)
        acc[mi][ni] = __builtin_amdgcn_mfma_f32_16x16x32_f16(bf[ni], acur[mi], acc[mi][ni], 0, 0, 0);
    if (PF) {
#pragma unroll
      for (int mi = 0; mi < MI; ++mi) acur[mi] = anext[mi];
    }
  }
}

// ---- row-major-A core (LDS staged both) — used only by bbuild (one-time) ----
__device__ inline void gemm_core_rm(const unsigned short* __restrict__ A,
                                    const unsigned short* __restrict__ Bn,
                                    int K, int m0, int n0, accv_t acc[4][4]) {
  __shared__ unsigned short ldsA[128 * 32];
  __shared__ unsigned short ldsB[128 * 32];
  const int tid = threadIdx.x;
  const int wave = tid >> 6, lane = tid & 63;
  const TC c = tcoords();
#pragma unroll
  for (int mi = 0; mi < 4; ++mi)
#pragma unroll
    for (int ni = 0; ni < 4; ++ni) acc[mi][ni] = (accv_t){0.f, 0.f, 0.f, 0.f};
  const int nkt = K >> 5;
  for (int kt = 0; kt < nkt; ++kt) {
    const int k0 = kt << 5;
    __syncthreads();
#pragma unroll
    for (int it = 0; it < 2; ++it) {
      int cbase = (it << 8) + (wave << 6);
      int chunk = cbase + lane;
      int row = chunk >> 2, kc = (chunk & 3) << 3;
      gld_lds16(&A[(size_t)(m0 + row) * K + k0 + kc], &ldsA[cbase * 8]);
      gld_lds16(&Bn[(size_t)(n0 + row) * K + k0 + kc], &ldsB[cbase * 8]);
    }
    __syncthreads();
    hfrag_t af[4], bf[4];
#pragma unroll
    for (int mi = 0; mi < 4; ++mi)
      af[mi] = *(const hfrag_t*)&ldsA[(c.wm + mi * 16 + c.l16) * 32 + c.quad * 8];
#pragma unroll
    for (int ni = 0; ni < 4; ++ni)
      bf[ni] = *(const hfrag_t*)&ldsB[(c.wn + ni * 16 + c.l16) * 32 + c.quad * 8];
#pragma unroll
    for (int mi = 0; mi < 4; ++mi)
#pragma unroll
      for (int ni = 0; ni < 4; ++ni)
        acc[mi][ni] = __builtin_amdgcn_mfma_f32_16x16x32_f16(bf[ni], af[mi], acc[mi][ni], 0, 0, 0);
  }
}

// epilogue coords (row-major targets): lane owns row m and 4 consecutive cols at nb
#define EPI_COORDS(c, m0, n0, mi, ni) \
  int m = (m0) + (c).wm + (mi) * 16 + (c).l16; \
  int nb = (n0) + (c).wn + (ni) * 16 + (c).quad * 4;

// ---------------- small kernels ----------------
__global__ void k_zero(float* slots) { if (threadIdx.x < 64) slots[threadIdx.x] = 0.f; }

__global__ void k_colnorm(const float* __restrict__ W, float* __restrict__ invn) {
  int j = blockIdx.x * 256 + threadIdx.x;     // 2048 cols
  float s = 0.f;
  for (int i = 0; i < DB; ++i) { float v = W[(size_t)i * NB + j]; s += v * v; }
  invn[j] = 1.0f / sqrtf(s);
}

// normalize cols + emit fp16 Wn[512][2048] and transposed Wt[2048][512]
__global__ void k_wnorm(const float* __restrict__ W, const float* __restrict__ invn,
                        unsigned short* __restrict__ Wn, unsigned short* __restrict__ Wt) {
  __shared__ unsigned short tile[32][33];
  int tx = threadIdx.x & 31, ty = threadIdx.x >> 5;
  int j = blockIdx.x * 32 + tx;               // n index
  float inv = invn[j];
#pragma unroll
  for (int r = 0; r < 4; ++r) {
    int i = blockIdx.y * 32 + ty + r * 8;     // row of W
    unsigned short h = f2h(W[(size_t)i * NB + j] * inv);
    Wn[(size_t)i * NB + j] = h;
    tile[ty + r * 8][tx] = h;
  }
  __syncthreads();
#pragma unroll
  for (int r = 0; r < 4; ++r) {
    int jj = blockIdx.x * 32 + ty + r * 8;    // Wt row (n)
    int ii = blockIdx.y * 32 + tx;            // Wt col (i)
    Wt[(size_t)jj * DB + ii] = tile[tx][ty + r * 8];
  }
}

// Y (row-major fp32) -> Yh (tiled fp16, NT=32) + ||Y||^2
__global__ void k_ynorm(const float* __restrict__ Y, unsigned short* __restrict__ Yh,
                        float* __restrict__ slots) {
  float s = 0.f;
  for (size_t t = (size_t)blockIdx.x * 256 + threadIdx.x; t < (size_t)(NR * DB / 4);
       t += (size_t)gridDim.x * 256) {
    int tile = (int)(t >> 6), lane = (int)(t & 63);
    int mt = tile >> 5, nt = tile & 31;                    // 32 n-tiles per row
    int m = mt * 16 + (lane & 15), n = nt * 16 + ((lane >> 4) << 2);
    f4 v = *(const f4*)&Y[(size_t)m * DB + n];
    us4 h;
#pragma unroll
    for (int r = 0; r < 4; ++r) { h[r] = f2h(v[r]); s += v[r] * v[r]; }
    *(us4*)&Yh[t << 2] = h;
  }
  for (int off = 32; off > 0; off >>= 1) s += __shfl_xor(s, off);
  if ((threadIdx.x & 63) == 0) atomicAdd(&slots[SL_Y2], s);
}

// fp32 squaring: D = (S/tr)^2, accumulate trace(D)
__global__ __launch_bounds__(256) void k_sq(const float* __restrict__ S, float* __restrict__ D,
                                            const float* __restrict__ trIn, float* __restrict__ trOut) {
  __shared__ float tA[32][33], tB[32][33];
  int tx = threadIdx.x & 31, ty = threadIdx.x >> 5;
  int r0 = blockIdx.y * 32, c0 = blockIdx.x * 32;
  float inv = 1.0f / trIn[0];
  float acc[4] = {0.f, 0.f, 0.f, 0.f};
  for (int kt = 0; kt < 16; ++kt) {
    __syncthreads();
#pragma unroll
    for (int r = 0; r < 4; ++r) {
      tA[ty + r * 8][tx] = S[(size_t)(r0 + ty + r * 8) * DB + kt * 32 + tx];
      tB[ty + r * 8][tx] = S[(size_t)(kt * 32 + ty + r * 8) * DB + c0 + tx];
    }
    __syncthreads();
#pragma unroll
    for (int kk = 0; kk < 32; ++kk) {
      float b = tB[kk][tx];
#pragma unroll
      for (int r = 0; r < 4; ++r) acc[r] += tA[ty + r * 8][kk] * b;
    }
  }
  float inv2 = inv * inv;
#pragma unroll
  for (int r = 0; r < 4; ++r) {
    int row = r0 + ty + r * 8, col = c0 + tx;
    float v = acc[r] * inv2;
    D[(size_t)row * DB + col] = v;
    if (row == col) atomicAdd(trOut, v);
  }
}

__global__ void k_rayleigh(const float* __restrict__ Bm, const float* __restrict__ S,
                           float* __restrict__ slots) {
  int tid = blockIdx.x * 256 + threadIdx.x;
  float num = 0.f, den = 0.f;
  for (int i = tid; i < DB * DB; i += 256 * 256) {
    float s = S[i];
    num += Bm[i] * s;
    if ((i >> 9) == (i & 511)) den += s;
  }
  for (int off = 32; off > 0; off >>= 1) { num += __shfl_xor(num, off); den += __shfl_xor(den, off); }
  if ((threadIdx.x & 63) == 0) { atomicAdd(&slots[SL_NUM], num); atomicAdd(&slots[SL_DEN], den); }
}

__global__ void k_derive(float* slots, const float* __restrict__ Kp) {
  if (threadIdx.x == 0) {
    float cc = slots[SL_NUM] / slots[SL_DEN];
    slots[SL_C] = cc;
    float eta = 1.0f / cc;
    slots[SL_ETA] = eta;
    slots[SL_THR] = Kp[0] * eta;
  }
}

__global__ void k_norms(const float* __restrict__ slots, float* __restrict__ out) {
  int i = threadIdx.x;
  if (i < ITERS) out[i] = sqrtf(slots[SL_RES2 + i] / slots[SL_Y2]);
}

// ---------------- GEMM kernels ----------------
// B = Wn * Wn^T  [512x512] row-major out, trace -> slots[SL_TR]
__global__ __launch_bounds__(256) void k_gemm_bbuild(const unsigned short* __restrict__ Wn,
                                                     float* __restrict__ Bm, float* __restrict__ slots) {
  accv_t acc[4][4];
  int m0 = blockIdx.y * 128, n0 = blockIdx.x * 128;
  gemm_core_rm(Wn, Wn, NB, m0, n0, acc);
  TC c = tcoords();
  float tr = 0.f;
#pragma unroll
  for (int mi = 0; mi < 4; ++mi)
#pragma unroll
    for (int ni = 0; ni < 4; ++ni) {
      EPI_COORDS(c, m0, n0, mi, ni);
      *(f4*)&Bm[(size_t)m * DB + nb] = acc[mi][ni];
#pragma unroll
      for (int r = 0; r < 4; ++r)
        if (m == nb + r) tr += acc[mi][ni][r];
    }
  if (tr != 0.f) atomicAdd(&slots[SL_TR], tr);
}

// Gamma0 = soft(eta * (Y @ Wn), lam); Gh = Zh = Gamma0 (tiled fp16, NT=128)
__global__ __launch_bounds__(256) void k_gemm_init(const unsigned short* __restrict__ Yh,
                                                   const unsigned short* __restrict__ Wt,
                                                   const float* __restrict__ slots,
                                                   const float* __restrict__ Kp,
                                                   unsigned short* __restrict__ Gh,
                                                   unsigned short* __restrict__ Zh) {
  accv_t acc[4][4];
  int m0 = blockIdx.y * 128, n0 = blockIdx.x * 128;
  TC c = tcoords();
  gemm_tA_db<4, 4, 0>(Yh, DB / 16, Wt, DB, m0, n0, c.wm, c.wn, acc);
  int lane4 = (c.quad * 16 + c.l16) << 2;
  float eta = slots[SL_ETA], lam = Kp[0];
#pragma unroll
  for (int mi = 0; mi < 4; ++mi)
#pragma unroll
    for (int ni = 0; ni < 4; ++ni) {
      size_t tb = tbase(m0 + c.wm + mi * 16, n0 + c.wn + ni * 16, NB / 16) + lane4;
      us4 gq;
#pragma unroll
      for (int r = 0; r < 4; ++r) gq[r] = f2h(softthr(acc[mi][ni][r] * eta, lam));
      *(us4*)&Gh[tb] = gq;
      *(us4*)&Zh[tb] = gq;
    }
}

// R = Z @ Wn^T - Y (all tiled) ; accumulate ||R||^2.  Block tile 64x128, grid (4,128).
__global__ __launch_bounds__(256) void k_gemm_res(const unsigned short* __restrict__ Zh,
                                                  const unsigned short* __restrict__ Wn,
                                                  const unsigned short* __restrict__ Yh,
                                                  unsigned short* __restrict__ Rh,
                                                  float* __restrict__ res2slot) {
  accv_t acc[4][2];
  int m0 = blockIdx.y * 64, n0 = blockIdx.x * 128;
  int wave = threadIdx.x >> 6, lane = threadIdx.x & 63;
  int l16 = lane & 15, quad = lane >> 4;
  int wn = wave << 5;                        // 4 waves x 32 cols
  gemm_tA_db<4, 2, 1>(Zh, NB / 16, Wn, NB, m0, n0, 0, wn, acc);
  int lane4 = (quad * 16 + l16) << 2;
  float s2 = 0.f;
#pragma unroll
  for (int mi = 0; mi < 4; ++mi)
#pragma unroll
    for (int ni = 0; ni < 2; ++ni) {
      size_t tb = tbase(m0 + mi * 16, n0 + wn + ni * 16, DB / 16) + lane4;
      us4 yq = *(const us4*)&Yh[tb];
      us4 rq;
#pragma unroll
      for (int r = 0; r < 4; ++r) {
        float rv = acc[mi][ni][r] - h2f(yq[r]);
        rq[r] = f2h(rv);
        s2 += rv * rv;
      }
      *(us4*)&Rh[tb] = rq;
    }
  for (int off = 32; off > 0; off >>= 1) s2 += __shfl_xor(s2, off);
  if ((threadIdx.x & 63) == 0) atomicAdd(res2slot, s2);
}

// G = R @ Wn ; gn = soft(Z - eta*G, lam/c); Z = gn + mom*(gn - Gamma_old); Gh = gn
// last iter: also write exact fp32 gn to GammaOut (row-major)
__global__ __launch_bounds__(256) void k_gemm_upd(const unsigned short* __restrict__ Rh,
                                                  const unsigned short* __restrict__ Wt,
                                                  const float* __restrict__ slots,
                                                  unsigned short* __restrict__ Gh,
                                                  unsigned short* __restrict__ Zh,
                                                  float* __restrict__ GammaOut,
                                                  float mom, int writeFinal) {
  accv_t acc[4][4];
  int m0 = blockIdx.y * 128, n0 = blockIdx.x * 128;
  TC c = tcoords();
  gemm_tA_db<4, 4, 0>(Rh, DB / 16, Wt, DB, m0, n0, c.wm, c.wn, acc);
  int lane4 = (c.quad * 16 + c.l16) << 2;
  float eta = slots[SL_ETA], thr = slots[SL_THR];
#pragma unroll
  for (int mi = 0; mi < 4; ++mi)
#pragma unroll
    for (int ni = 0; ni < 4; ++ni) {
      size_t tb = tbase(m0 + c.wm + mi * 16, n0 + c.wn + ni * 16, NB / 16) + lane4;
      us4 zq = *(const us4*)&Zh[tb];
      us4 gq = *(const us4*)&Gh[tb];
      us4 gho, zho;
      f4 gf;
#pragma unroll
      for (int r = 0; r < 4; ++r) {
        float z = h2f(zq[r]);
        float gold = h2f(gq[r]);
        float gn = softthr(z - eta * acc[mi][ni][r], thr);
        float zn = gn + mom * (gn - gold);
        gho[r] = f2h(gn);
        zho[r] = f2h(zn);
        gf[r] = gn;
      }
      *(us4*)&Gh[tb] = gho;
      *(us4*)&Zh[tb] = zho;
      if (writeFinal) {
        EPI_COORDS(c, m0, n0, mi, ni);
        *(f4*)&GammaOut[(size_t)m * NB + nb] = gf;
      }
    }
}

// X = Gamma @ Wn^T (row-major fp32 out)
__global__ __launch_bounds__(256) void k_gemm_x(const unsigned short* __restrict__ Gh,
                                                const unsigned short* __restrict__ Wn,
                                                float* __restrict__ X) {
  accv_t acc[4][4];
  int m0 = blockIdx.y * 128, n0 = blockIdx.x * 128;
  TC c = tcoords();
  gemm_tA_db<4, 4, 0>(Gh, NB / 16, Wn, NB, m0, n0, c.wm, c.wn, acc);
#pragma unroll
  for (int mi = 0; mi < 4; ++mi)
#pragma unroll
    for (int ni = 0; ni < 4; ++ni) {
      EPI_COORDS(c, m0, n0, mi, ni);
      *(f4*)&X[(size_t)m * DB + nb] = acc[mi][ni];
    }
}

extern "C" void kernel_launch(void* const* d_in, const int* in_sizes, int n_in,
                              void* d_out, int out_size, void* d_ws, size_t ws_size,
                              hipStream_t stream) {
  const float* Y  = (const float*)d_in[0];
  const float* W  = (const float*)d_in[1];
  const float* Kp = (const float*)d_in[2];

  float* Xout     = (float*)d_out;
  float* GammaOut = Xout + (size_t)NR * DB;
  float* NormsOut = GammaOut + (size_t)NR * NB;

  char* p = (char*)d_ws;
  auto carve = [&](size_t bytes) -> void* {
    void* r = (void*)p; p += (bytes + 255) & ~(size_t)255; return r;
  };
  float* slots = (float*)carve(64 * 4);
  float* invn  = (float*)carve(NB * 4);
  float* Bmat  = (float*)carve((size_t)DB * DB * 4);
  float* S0    = (float*)carve((size_t)DB * DB * 4);
  float* S1    = (float*)carve((size_t)DB * DB * 4);
  unsigned short* Wn  = (unsigned short*)carve((size_t)DB * NB * 2);
  unsigned short* Wt  = (unsigned short*)carve((size_t)NB * DB * 2);
  unsigned short* Yh  = (unsigned short*)carve((size_t)NR * DB * 2);
  unsigned short* Rh  = (unsigned short*)carve((size_t)NR * DB * 2);
  unsigned short* Zh  = (unsigned short*)carve((size_t)NR * NB * 2);
  unsigned short* Gh  = (unsigned short*)carve((size_t)NR * NB * 2);

  k_zero<<<1, 64, 0, stream>>>(slots);
  k_colnorm<<<NB / 256, 256, 0, stream>>>(W, invn);
  k_wnorm<<<dim3(NB / 32, DB / 32), 256, 0, stream>>>(W, invn, Wn, Wt);
  k_ynorm<<<1024, 256, 0, stream>>>(Y, Yh, slots);

  // power method replacement: B = Wn Wn^T, then 9 trace-normalized squarings + Rayleigh trace ratio
  k_gemm_bbuild<<<dim3(DB / 128, DB / 128), 256, 0, stream>>>(Wn, Bmat, slots);
  float* ss[2] = {S0, S1};
  for (int k = 0; k < NSQ; ++k) {
    const float* in = (k == 0) ? Bmat : ss[(k + 1) & 1];
    k_sq<<<dim3(16, 16), 256, 0, stream>>>(in, ss[k & 1], slots + SL_TR + k, slots + SL_TR + k + 1);
  }
  k_rayleigh<<<256, 256, 0, stream>>>(Bmat, ss[(NSQ + 1) & 1], slots);
  k_derive<<<1, 64, 0, stream>>>(slots, Kp);

  // FISTA
  k_gemm_init<<<dim3(NB / 128, NR / 128), 256, 0, stream>>>(Yh, Wt, slots, Kp, Gh, Zh);
  double t = 1.0;
  for (int i = 0; i < ITERS; ++i) {
    k_gemm_res<<<dim3(DB / 128, NR / 64), 256, 0, stream>>>(Zh, Wn, Yh, Rh, slots + SL_RES2 + i);
    double tn = (1.0 + sqrt(1.0 + 4.0 * t * t)) / 2.0;
    float mom = (float)((t - 1.0) / tn);
    t = tn;
    k_gemm_upd<<<dim3(NB / 128, NR / 128), 256, 0, stream>>>(Rh, Wt, slots, Gh, Zh, GammaOut,
                                                             mom, (i == ITERS - 1) ? 1 : 0);
  }
  k_gemm_x<<<dim3(DB / 128, NR / 128), 256, 0, stream>>>(Gh, Wn, Xout);
  k_norms<<<1, 64, 0, stream>>>(slots, NormsOut);
}

// Round 7
// 2650.850 us; speedup vs baseline: 1.1531x; 1.1531x over previous
//
#include <hip/hip_runtime.h>
#include <cmath>

#define NR   8192   // rows of Y
#define DB   512    // signal dim n
#define NB   2048   // dictionary atoms m
#define ITERS 20
#define NSQ   9     // trace-normalized squarings of B

typedef _Float16 hfrag_t __attribute__((ext_vector_type(8)));  // 8 fp16 = 16B
typedef __attribute__((ext_vector_type(4))) float accv_t;      // 4 fp32
typedef unsigned short us4 __attribute__((ext_vector_type(4))); // 8B
typedef float f4 __attribute__((ext_vector_type(4)));           // 16B

// scalar slots in ws
#define SL_Y2   0
#define SL_NUM  1
#define SL_DEN  2
#define SL_C    3
#define SL_ETA  4
#define SL_THR  5
#define SL_TR   6    // 6..15  traces
#define SL_RES2 16   // 16..35 per-iter ||R||^2

__device__ inline unsigned short f2h(float f) {
  _Float16 h = (_Float16)f;
  return __builtin_bit_cast(unsigned short, h);
}
__device__ inline float h2f(unsigned short u) {
  _Float16 h = __builtin_bit_cast(_Float16, u);
  return (float)h;
}
__device__ inline float softthr(float x, float t) {
  float a = fabsf(x) - t;
  return a > 0.f ? copysignf(a, x) : 0.f;
}

// ---- Fragment-native tiled layout ----
// 16x16 tile = 256 contiguous fp16, element (m,k) at m*16+k (row-major in tile).
// A-fragment for mfma_16x16x32 (operand-swapped): lane (l16,quad) needs
// A[m=l16][k=quad*8+j] j=0..7 -> tile kt*2+(quad>>1), bytes l16*32+(quad&1)*16:
// ONE 16B load per fragment; wave covers 512B contiguous. Same for B (n,k).
// C tile: lane owns (m=l16, n=quad*4+r) -> us4 at byte l16*32+quad*8.

// ---- barrier-free MFMA GEMM core: both operands tiled, no LDS ----
template<int MI, int NI, int NKT>
__device__ inline void gemm_tt(const unsigned short* __restrict__ At, int NTka,
                               const unsigned short* __restrict__ Bt, int NTkb,
                               int mt0, int nt0, accv_t acc[MI][NI]) {
  const int lane = threadIdx.x & 63;
  const int l16 = lane & 15, quad = lane >> 4;
  const int off = l16 * 16 + (quad & 1) * 8;   // element offset within tile
  const int kh = quad >> 1;
#pragma unroll
  for (int mi = 0; mi < MI; ++mi)
#pragma unroll
    for (int ni = 0; ni < NI; ++ni) acc[mi][ni] = (accv_t){0.f, 0.f, 0.f, 0.f};

#pragma unroll 4
  for (int kt = 0; kt < NKT; ++kt) {
    const int ktile = (kt << 1) + kh;
    hfrag_t af[MI], bf[NI];
#pragma unroll
    for (int mi = 0; mi < MI; ++mi)
      af[mi] = *(const hfrag_t*)&At[(((size_t)(mt0 + mi) * NTka + ktile) << 8) + off];
#pragma unroll
    for (int ni = 0; ni < NI; ++ni)
      bf[ni] = *(const hfrag_t*)&Bt[(((size_t)(nt0 + ni) * NTkb + ktile) << 8) + off];
#pragma unroll
    for (int mi = 0; mi < MI; ++mi)
#pragma unroll
      for (int ni = 0; ni < NI; ++ni)
        acc[mi][ni] = __builtin_amdgcn_mfma_f32_16x16x32_f16(bf[ni], af[mi], acc[mi][ni], 0, 0, 0);
  }
}

// C-tile epilogue offset (element units) for tiled fp16 surfaces
__device__ inline size_t ctile_off(int mt, int nt, int NTn) {
  int lane = threadIdx.x & 63;
  return (((size_t)mt * NTn + nt) << 8) + (lane & 15) * 16 + (lane >> 4) * 4;
}

// ---------------- small kernels ----------------
__global__ void k_zero(float* slots) { if (threadIdx.x < 64) slots[threadIdx.x] = 0.f; }

__global__ void k_colnorm(const float* __restrict__ W, float* __restrict__ invn) {
  int j = blockIdx.x * 256 + threadIdx.x;     // 2048 cols
  float s = 0.f;
  for (int i = 0; i < DB; ++i) { float v = W[(size_t)i * NB + j]; s += v * v; }
  invn[j] = 1.0f / sqrtf(s);
}

// normalize cols; emit tiled Wn_t [DB/16][NB/16] (elem (i,j)->i*16+j)
// and tiled Wt_t [NB/16][DB/16] (elem (j,i)->j*16+i)
__global__ void k_wnorm(const float* __restrict__ W, const float* __restrict__ invn,
                        unsigned short* __restrict__ Wn_t, unsigned short* __restrict__ Wt_t) {
  int tx = threadIdx.x & 31, ty = threadIdx.x >> 5;
  int j = blockIdx.x * 32 + tx;               // NB index
  float inv = invn[j];
#pragma unroll
  for (int r = 0; r < 4; ++r) {
    int i = blockIdx.y * 32 + ty + r * 8;     // DB index
    unsigned short h = f2h(W[(size_t)i * NB + j] * inv);
    Wn_t[(((size_t)(i >> 4) * (NB / 16) + (j >> 4)) << 8) + (i & 15) * 16 + (j & 15)] = h;
    Wt_t[(((size_t)(j >> 4) * (DB / 16) + (i >> 4)) << 8) + (j & 15) * 16 + (i & 15)] = h;
  }
}

// Y (row-major fp32) -> Yh (tiled fp16, 32 k-tiles per row) + ||Y||^2
__global__ void k_ynorm(const float* __restrict__ Y, unsigned short* __restrict__ Yh,
                        float* __restrict__ slots) {
  float s = 0.f;
  for (size_t u = (size_t)blockIdx.x * 256 + threadIdx.x; u < (size_t)(NR * DB / 4);
       u += (size_t)gridDim.x * 256) {
    int tile = (int)(u >> 6), r = (int)(u & 63);
    int mt = tile >> 5, nt = tile & 31;
    int m = mt * 16 + (r >> 2), n = nt * 16 + (r & 3) * 4;
    f4 v = *(const f4*)&Y[(size_t)m * DB + n];
    us4 h;
#pragma unroll
    for (int q = 0; q < 4; ++q) { h[q] = f2h(v[q]); s += v[q] * v[q]; }
    *(us4*)&Yh[u << 2] = h;
  }
  for (int off = 32; off > 0; off >>= 1) s += __shfl_xor(s, off);
  if ((threadIdx.x & 63) == 0) atomicAdd(&slots[SL_Y2], s);
}

// fp32 squaring: D = (S/tr)^2, accumulate trace(D)
__global__ __launch_bounds__(256) void k_sq(const float* __restrict__ S, float* __restrict__ D,
                                            const float* __restrict__ trIn, float* __restrict__ trOut) {
  __shared__ float tA[32][33], tB[32][33];
  int tx = threadIdx.x & 31, ty = threadIdx.x >> 5;
  int r0 = blockIdx.y * 32, c0 = blockIdx.x * 32;
  float inv = 1.0f / trIn[0];
  float acc[4] = {0.f, 0.f, 0.f, 0.f};
  for (int kt = 0; kt < 16; ++kt) {
    __syncthreads();
#pragma unroll
    for (int r = 0; r < 4; ++r) {
      tA[ty + r * 8][tx] = S[(size_t)(r0 + ty + r * 8) * DB + kt * 32 + tx];
      tB[ty + r * 8][tx] = S[(size_t)(kt * 32 + ty + r * 8) * DB + c0 + tx];
    }
    __syncthreads();
#pragma unroll
    for (int kk = 0; kk < 32; ++kk) {
      float b = tB[kk][tx];
#pragma unroll
      for (int r = 0; r < 4; ++r) acc[r] += tA[ty + r * 8][kk] * b;
    }
  }
  float inv2 = inv * inv;
#pragma unroll
  for (int r = 0; r < 4; ++r) {
    int row = r0 + ty + r * 8, col = c0 + tx;
    float v = acc[r] * inv2;
    D[(size_t)row * DB + col] = v;
    if (row == col) atomicAdd(trOut, v);
  }
}

__global__ void k_rayleigh(const float* __restrict__ Bm, const float* __restrict__ S,
                           float* __restrict__ slots) {
  int tid = blockIdx.x * 256 + threadIdx.x;
  float num = 0.f, den = 0.f;
  for (int i = tid; i < DB * DB; i += 256 * 256) {
    float s = S[i];
    num += Bm[i] * s;
    if ((i >> 9) == (i & 511)) den += s;
  }
  for (int off = 32; off > 0; off >>= 1) { num += __shfl_xor(num, off); den += __shfl_xor(den, off); }
  if ((threadIdx.x & 63) == 0) { atomicAdd(&slots[SL_NUM], num); atomicAdd(&slots[SL_DEN], den); }
}

__global__ void k_derive(float* slots, const float* __restrict__ Kp) {
  if (threadIdx.x == 0) {
    float cc = slots[SL_NUM] / slots[SL_DEN];
    slots[SL_C] = cc;
    float eta = 1.0f / cc;
    slots[SL_ETA] = eta;
    slots[SL_THR] = Kp[0] * eta;
  }
}

__global__ void k_norms(const float* __restrict__ slots, float* __restrict__ out) {
  int i = threadIdx.x;
  if (i < ITERS) out[i] = sqrtf(slots[SL_RES2 + i] / slots[SL_Y2]);
}

// ---------------- GEMM kernels (all barrier-free) ----------------
// B = Wn * Wn^T [512x512] row-major out, trace -> slots[SL_TR].
// block 128m x 64n: wave w covers mt0=8*by+w*2 (MI=2), nt0=4*bx (NI=4)
__global__ __launch_bounds__(256) void k_gemm_bbuild(const unsigned short* __restrict__ Wn_t,
                                                     float* __restrict__ Bm, float* __restrict__ slots) {
  accv_t acc[2][4];
  int w = threadIdx.x >> 6, lane = threadIdx.x & 63;
  int mt0 = blockIdx.y * 8 + w * 2, nt0 = blockIdx.x * 4;
  gemm_tt<2, 4, NB / 32>(Wn_t, NB / 16, Wn_t, NB / 16, mt0, nt0, acc);
  int l16 = lane & 15, quad = lane >> 4;
  float tr = 0.f;
#pragma unroll
  for (int mi = 0; mi < 2; ++mi)
#pragma unroll
    for (int ni = 0; ni < 4; ++ni) {
      int m = (mt0 + mi) * 16 + l16, nb = (nt0 + ni) * 16 + quad * 4;
      *(f4*)&Bm[(size_t)m * DB + nb] = acc[mi][ni];
#pragma unroll
      for (int r = 0; r < 4; ++r)
        if (m == nb + r) tr += acc[mi][ni][r];
    }
  if (tr != 0.f) atomicAdd(&slots[SL_TR], tr);
}

// Gamma0 = soft(eta*(Y@Wn), lam); Gh = Zh = Gamma0 (tiled). block 128x128, wave 64x64.
__global__ __launch_bounds__(256) void k_gemm_init(const unsigned short* __restrict__ Yh,
                                                   const unsigned short* __restrict__ Wt_t,
                                                   const float* __restrict__ slots,
                                                   const float* __restrict__ Kp,
                                                   unsigned short* __restrict__ Gh,
                                                   unsigned short* __restrict__ Zh) {
  accv_t acc[4][4];
  int w = threadIdx.x >> 6;
  int mt0 = blockIdx.y * 8 + (w >> 1) * 4, nt0 = blockIdx.x * 8 + (w & 1) * 4;
  gemm_tt<4, 4, DB / 32>(Yh, DB / 16, Wt_t, DB / 16, mt0, nt0, acc);
  float eta = slots[SL_ETA], lam = Kp[0];
#pragma unroll
  for (int mi = 0; mi < 4; ++mi)
#pragma unroll
    for (int ni = 0; ni < 4; ++ni) {
      size_t tb = ctile_off(mt0 + mi, nt0 + ni, NB / 16);
      us4 gq;
#pragma unroll
      for (int r = 0; r < 4; ++r) gq[r] = f2h(softthr(acc[mi][ni][r] * eta, lam));
      *(us4*)&Gh[tb] = gq;
      *(us4*)&Zh[tb] = gq;
    }
}

// R = Z @ Wn^T - Y (tiled); ||R||^2. block 128m x 64n, wave 32x64 (MI=2,NI=4).
__global__ __launch_bounds__(256) void k_gemm_res(const unsigned short* __restrict__ Zh,
                                                  const unsigned short* __restrict__ Wn_t,
                                                  const unsigned short* __restrict__ Yh,
                                                  unsigned short* __restrict__ Rh,
                                                  float* __restrict__ res2slot) {
  accv_t acc[2][4];
  int w = threadIdx.x >> 6;
  int mt0 = blockIdx.y * 8 + w * 2, nt0 = blockIdx.x * 4;
  gemm_tt<2, 4, NB / 32>(Zh, NB / 16, Wn_t, NB / 16, mt0, nt0, acc);
  float s2 = 0.f;
#pragma unroll
  for (int mi = 0; mi < 2; ++mi)
#pragma unroll
    for (int ni = 0; ni < 4; ++ni) {
      size_t tb = ctile_off(mt0 + mi, nt0 + ni, DB / 16);
      us4 yq = *(const us4*)&Yh[tb];
      us4 rq;
#pragma unroll
      for (int r = 0; r < 4; ++r) {
        float rv = acc[mi][ni][r] - h2f(yq[r]);
        rq[r] = f2h(rv);
        s2 += rv * rv;
      }
      *(us4*)&Rh[tb] = rq;
    }
  for (int off = 32; off > 0; off >>= 1) s2 += __shfl_xor(s2, off);
  if ((threadIdx.x & 63) == 0) atomicAdd(res2slot, s2);
}

// G = R @ Wn ; gn = soft(Z - eta*G, lam/c); Z = gn + mom*(gn-Gamma_old); Gh = gn.
// block 128x128, wave 64x64. last iter: exact fp32 gn -> GammaOut (row-major).
__global__ __launch_bounds__(256) void k_gemm_upd(const unsigned short* __restrict__ Rh,
                                                  const unsigned short* __restrict__ Wt_t,
                                                  const float* __restrict__ slots,
                                                  unsigned short* __restrict__ Gh,
                                                  unsigned short* __restrict__ Zh,
                                                  float* __restrict__ GammaOut,
                                                  float mom, int writeFinal) {
  accv_t acc[4][4];
  int w = threadIdx.x >> 6, lane = threadIdx.x & 63;
  int mt0 = blockIdx.y * 8 + (w >> 1) * 4, nt0 = blockIdx.x * 8 + (w & 1) * 4;
  gemm_tt<4, 4, DB / 32>(Rh, DB / 16, Wt_t, DB / 16, mt0, nt0, acc);
  int l16 = lane & 15, quad = lane >> 4;
  float eta = slots[SL_ETA], thr = slots[SL_THR];
#pragma unroll
  for (int mi = 0; mi < 4; ++mi)
#pragma unroll
    for (int ni = 0; ni < 4; ++ni) {
      size_t tb = ctile_off(mt0 + mi, nt0 + ni, NB / 16);
      us4 zq = *(const us4*)&Zh[tb];
      us4 gq = *(const us4*)&Gh[tb];
      us4 gho, zho;
      f4 gf;
#pragma unroll
      for (int r = 0; r < 4; ++r) {
        float z = h2f(zq[r]);
        float gold = h2f(gq[r]);
        float gn = softthr(z - eta * acc[mi][ni][r], thr);
        float zn = gn + mom * (gn - gold);
        gho[r] = f2h(gn);
        zho[r] = f2h(zn);
        gf[r] = gn;
      }
      *(us4*)&Gh[tb] = gho;
      *(us4*)&Zh[tb] = zho;
      if (writeFinal) {
        int m = (mt0 + mi) * 16 + l16, nb = (nt0 + ni) * 16 + quad * 4;
        *(f4*)&GammaOut[(size_t)m * NB + nb] = gf;
      }
    }
}

// X = Gamma @ Wn^T (row-major fp32 out). block 128m x 64n, wave 32x64.
__global__ __launch_bounds__(256) void k_gemm_x(const unsigned short* __restrict__ Gh,
                                                const unsigned short* __restrict__ Wn_t,
                                                float* __restrict__ X) {
  accv_t acc[2][4];
  int w = threadIdx.x >> 6, lane = threadIdx.x & 63;
  int mt0 = blockIdx.y * 8 + w * 2, nt0 = blockIdx.x * 4;
  gemm_tt<2, 4, NB / 32>(Gh, NB / 16, Wn_t, NB / 16, mt0, nt0, acc);
  int l16 = lane & 15, quad = lane >> 4;
#pragma unroll
  for (int mi = 0; mi < 2; ++mi)
#pragma unroll
    for (int ni = 0; ni < 4; ++ni) {
      int m = (mt0 + mi) * 16 + l16, nb = (nt0 + ni) * 16 + quad * 4;
      *(f4*)&X[(size_t)m * DB + nb] = acc[mi][ni];
    }
}

extern "C" void kernel_launch(void* const* d_in, const int* in_sizes, int n_in,
                              void* d_out, int out_size, void* d_ws, size_t ws_size,
                              hipStream_t stream) {
  const float* Y  = (const float*)d_in[0];
  const float* W  = (const float*)d_in[1];
  const float* Kp = (const float*)d_in[2];

  float* Xout     = (float*)d_out;
  float* GammaOut = Xout + (size_t)NR * DB;
  float* NormsOut = GammaOut + (size_t)NR * NB;

  char* p = (char*)d_ws;
  auto carve = [&](size_t bytes) -> void* {
    void* r = (void*)p; p += (bytes + 255) & ~(size_t)255; return r;
  };
  float* slots = (float*)carve(64 * 4);
  float* invn  = (float*)carve(NB * 4);
  float* Bmat  = (float*)carve((size_t)DB * DB * 4);
  float* S0    = (float*)carve((size_t)DB * DB * 4);
  float* S1    = (float*)carve((size_t)DB * DB * 4);
  unsigned short* Wn_t = (unsigned short*)carve((size_t)DB * NB * 2);
  unsigned short* Wt_t = (unsigned short*)carve((size_t)NB * DB * 2);
  unsigned short* Yh   = (unsigned short*)carve((size_t)NR * DB * 2);
  unsigned short* Rh   = (unsigned short*)carve((size_t)NR * DB * 2);
  unsigned short* Zh   = (unsigned short*)carve((size_t)NR * NB * 2);
  unsigned short* Gh   = (unsigned short*)carve((size_t)NR * NB * 2);

  k_zero<<<1, 64, 0, stream>>>(slots);
  k_colnorm<<<NB / 256, 256, 0, stream>>>(W, invn);
  k_wnorm<<<dim3(NB / 32, DB / 32), 256, 0, stream>>>(W, invn, Wn_t, Wt_t);
  k_ynorm<<<1024, 256, 0, stream>>>(Y, Yh, slots);

  // power method replacement: B = Wn Wn^T, then 9 trace-normalized squarings + Rayleigh
  k_gemm_bbuild<<<dim3(DB / 64, DB / 128), 256, 0, stream>>>(Wn_t, Bmat, slots);
  float* ss[2] = {S0, S1};
  for (int k = 0; k < NSQ; ++k) {
    const float* in = (k == 0) ? Bmat : ss[(k + 1) & 1];
    k_sq<<<dim3(16, 16), 256, 0, stream>>>(in, ss[k & 1], slots + SL_TR + k, slots + SL_TR + k + 1);
  }
  k_rayleigh<<<256, 256, 0, stream>>>(Bmat, ss[(NSQ + 1) & 1], slots);
  k_derive<<<1, 64, 0, stream>>>(slots, Kp);

  // FISTA
  k_gemm_init<<<dim3(NB / 128, NR / 128), 256, 0, stream>>>(Yh, Wt_t, slots, Kp, Gh, Zh);
  double t = 1.0;
  for (int i = 0; i < ITERS; ++i) {
    k_gemm_res<<<dim3(DB / 64, NR / 128), 256, 0, stream>>>(Zh, Wn_t, Yh, Rh, slots + SL_RES2 + i);
    double tn = (1.0 + sqrt(1.0 + 4.0 * t * t)) / 2.0;
    float mom = (float)((t - 1.0) / tn);
    t = tn;
    k_gemm_upd<<<dim3(NB / 128, NR / 128), 256, 0, stream>>>(Rh, Wt_t, slots, Gh, Zh, GammaOut,
                                                             mom, (i == ITERS - 1) ? 1 : 0);
  }
  k_gemm_x<<<dim3(DB / 64, NR / 128), 256, 0, stream>>>(Gh, Wn_t, Xout);
  k_norms<<<1, 64, 0, stream>>>(slots, NormsOut);
}